// Round 1
// baseline (1307.668 us; speedup 1.0000x reference)
//
#include <hip/hip_runtime.h>
#include <stdint.h>

#define NHEADS 16
#define LKK 8192

typedef __attribute__((ext_vector_type(8))) short short8;
typedef __attribute__((ext_vector_type(4))) float f32x4;
typedef __attribute__((ext_vector_type(4))) unsigned short ushort4v;

__device__ __forceinline__ unsigned short f2bf(float f) {
  union { float f; unsigned u; } v; v.f = f;
  unsigned u = v.u;
  return (unsigned short)((u + 0x7fffu + ((u >> 16) & 1u)) >> 16);
}

__device__ __forceinline__ void async_ld16(const void* g, void* l) {
  __builtin_amdgcn_global_load_lds(
      (const __attribute__((address_space(1))) unsigned int*)g,
      (__attribute__((address_space(3))) unsigned int*)l, 16, 0, 0);
}

// C = A(fp32,[M x 1024]) @ Bw(bf16,[1024 x 1024])^T + bias, NT GEMM.
// MODE 0: fp32 row-major out. MODE 1: bf16 out [b][h][x][d] (ROWS=1<<LOG2ROWS).
// MODE 2: bf16 out transposed [b][h][d][x].
template <int MODE, int LOG2ROWS>
__global__ __launch_bounds__(256) void gemm_nt(
    const float* __restrict__ A, const unsigned short* __restrict__ Bw,
    const float* __restrict__ bias, float scale, void* __restrict__ outp) {
  __shared__ unsigned short As[128 * 32];
  __shared__ unsigned short Bs[128 * 32];

  const int tid = threadIdx.x;
  const int wave = tid >> 6, lane = tid & 63;
  const int quad = lane >> 4, l16 = lane & 15;
  const int wr = wave >> 1, wc = wave & 1;
  const int bm = blockIdx.x, bn = blockIdx.y;

  f32x4 acc[4][4] = {};

  const int a_seg = tid & 7;    // which 4-float segment of a 32-float row
  const int a_row0 = tid >> 3;  // 0..31
  const float* Abase = A + (size_t)(bm * 128) * 1024 + a_seg * 4;

  const int b_rl = lane >> 2;  // 0..15 rows within 16-row group
  const int b_ks = lane & 3;   // 8-bf16 segment
  const unsigned short* Bbase =
      Bw + (size_t)(bn * 128 + wave * 32 + b_rl) * 1024 + b_ks * 8;
  unsigned short* BsBase = Bs + (wave * 32) * 32;  // + lane*8 elems implicit

  for (int kk = 0; kk < 32; ++kk) {
    const int k0 = kk * 32;
    float4 ar[4];
#pragma unroll
    for (int r = 0; r < 4; ++r)
      ar[r] = *(const float4*)(Abase + (size_t)(a_row0 + r * 32) * 1024 + k0);

    __syncthreads();  // protect LDS from previous iter's readers

    async_ld16(Bbase + k0, BsBase);
    async_ld16(Bbase + 16 * 1024 + k0, BsBase + 16 * 32);

#pragma unroll
    for (int r = 0; r < 4; ++r) {
      ushort4v pk = {f2bf(ar[r].x), f2bf(ar[r].y), f2bf(ar[r].z), f2bf(ar[r].w)};
      *(ushort4v*)(As + (a_row0 + r * 32) * 32 + a_seg * 4) = pk;
    }

    __syncthreads();  // drains vmcnt (async B) + lgkm (A writes)

    short8 af[4], bf[4];
#pragma unroll
    for (int i = 0; i < 4; ++i)
      af[i] = *(const short8*)(As + (wr * 64 + i * 16 + l16) * 32 + quad * 8);
#pragma unroll
    for (int j = 0; j < 4; ++j)
      bf[j] = *(const short8*)(Bs + (wc * 64 + j * 16 + l16) * 32 + quad * 8);
#pragma unroll
    for (int i = 0; i < 4; ++i)
#pragma unroll
      for (int j = 0; j < 4; ++j)
        acc[i][j] =
            __builtin_amdgcn_mfma_f32_16x16x32_bf16(af[i], bf[j], acc[i][j], 0, 0, 0);
  }

  float bvals[4];
#pragma unroll
  for (int j = 0; j < 4; ++j) bvals[j] = bias[bn * 128 + wc * 64 + j * 16 + l16];

#pragma unroll
  for (int i = 0; i < 4; ++i) {
    const int gm0 = bm * 128 + wr * 64 + i * 16 + quad * 4;
#pragma unroll
    for (int j = 0; j < 4; ++j) {
      const int gn = bn * 128 + wc * 64 + j * 16 + l16;
      float vals[4];
#pragma unroll
      for (int r = 0; r < 4; ++r) vals[r] = (acc[i][j][r] + bvals[j]) * scale;
      if constexpr (MODE == 0) {
        float* O = (float*)outp;
#pragma unroll
        for (int r = 0; r < 4; ++r) O[(size_t)(gm0 + r) * 1024 + gn] = vals[r];
      } else if constexpr (MODE == 1) {
        unsigned short* O = (unsigned short*)outp;
        const int h = gn >> 6, d = gn & 63;
#pragma unroll
        for (int r = 0; r < 4; ++r) {
          const int m = gm0 + r;
          const int bb = m >> LOG2ROWS;
          const int x = m & ((1 << LOG2ROWS) - 1);
          O[((((size_t)(bb * 16 + h)) << LOG2ROWS) + x) * 64 + d] = f2bf(vals[r]);
        }
      } else {
        unsigned short* O = (unsigned short*)outp;
        const int h = gn >> 6, d = gn & 63;
        const int bb = gm0 >> LOG2ROWS;
        const int x = gm0 & ((1 << LOG2ROWS) - 1);
        ushort4v pk = {f2bf(vals[0]), f2bf(vals[1]), f2bf(vals[2]), f2bf(vals[3])};
        *(ushort4v*)(O + ((((size_t)(bb * 16 + h)) * 64 + d) << LOG2ROWS) + x) = pk;
      }
    }
  }
}

// Flash attention: grid (h=16, b=8), 256 threads; wave w owns keys [w*2048, +2048).
__global__ __launch_bounds__(256) void attn_kernel(
    const unsigned short* __restrict__ q_hd,  // [B][H][16][64] bf16 (scale folded)
    const unsigned short* __restrict__ k_hd,  // [B][H][8192][64] bf16
    const unsigned short* __restrict__ v_t,   // [B][H][64][8192] bf16
    float* __restrict__ attn)                 // [128][1024] fp32
{
  __shared__ unsigned short p_lds[4][16 * 32];
  __shared__ float o_lds[4][16][64];
  __shared__ float ml_lds[4][2][16];

  const int h = blockIdx.x, b = blockIdx.y;
  const int tid = threadIdx.x, wave = tid >> 6, lane = tid & 63;
  const int quad = lane >> 4, l16 = lane & 15;
  const size_t bh = (size_t)(b * NHEADS + h);
  const float LOG2E = 1.44269504088896f;

  const unsigned short* qb = q_hd + bh * (16 * 64) + l16 * 64 + quad * 8;
  short8 aq0 = *(const short8*)(qb);
  short8 aq1 = *(const short8*)(qb + 32);

  const unsigned short* kb_base = k_hd + bh * ((size_t)LKK * 64);
  const unsigned short* vb_base = v_t + bh * ((size_t)64 * LKK);

  float ms[4], ls[4];
  f32x4 o[4] = {};
#pragma unroll
  for (int r = 0; r < 4; ++r) { ms[r] = -3.0e38f; ls[r] = 0.f; }

  unsigned short* pw = &p_lds[wave][0];

  for (int c = 0; c < 64; ++c) {
    const int j0 = wave * 2048 + c * 32;
    short8 kf[2][2];
#pragma unroll
    for (int jt = 0; jt < 2; ++jt)
#pragma unroll
      for (int dh = 0; dh < 2; ++dh)
        kf[jt][dh] = *(const short8*)(kb_base + (size_t)(j0 + jt * 16 + l16) * 64 +
                                      dh * 32 + quad * 8);
    f32x4 s[2];
#pragma unroll
    for (int jt = 0; jt < 2; ++jt) {
      f32x4 z = {};
      z = __builtin_amdgcn_mfma_f32_16x16x32_bf16(aq0, kf[jt][0], z, 0, 0, 0);
      z = __builtin_amdgcn_mfma_f32_16x16x32_bf16(aq1, kf[jt][1], z, 0, 0, 0);
      s[jt] = z;
    }
    float p0[4], p1[4], alpha[4];
#pragma unroll
    for (int r = 0; r < 4; ++r) {
      float v = fmaxf(s[0][r], s[1][r]);
      v = fmaxf(v, __shfl_xor(v, 1));
      v = fmaxf(v, __shfl_xor(v, 2));
      v = fmaxf(v, __shfl_xor(v, 4));
      v = fmaxf(v, __shfl_xor(v, 8));
      const float mn = fmaxf(ms[r], v);
      alpha[r] = __builtin_amdgcn_exp2f((ms[r] - mn) * LOG2E);
      p0[r] = __builtin_amdgcn_exp2f((s[0][r] - mn) * LOG2E);
      p1[r] = __builtin_amdgcn_exp2f((s[1][r] - mn) * LOG2E);
      float rs = p0[r] + p1[r];
      rs += __shfl_xor(rs, 1);
      rs += __shfl_xor(rs, 2);
      rs += __shfl_xor(rs, 4);
      rs += __shfl_xor(rs, 8);
      ls[r] = ls[r] * alpha[r] + rs;
      ms[r] = mn;
    }
#pragma unroll
    for (int dt = 0; dt < 4; ++dt) {
      f32x4 t = o[dt];
      t[0] *= alpha[0]; t[1] *= alpha[1]; t[2] *= alpha[2]; t[3] *= alpha[3];
      o[dt] = t;
    }
    // P: C-layout -> LDS (bf16) -> A-layout
#pragma unroll
    for (int r = 0; r < 4; ++r) {
      pw[(quad * 4 + r) * 32 + l16] = f2bf(p0[r]);
      pw[(quad * 4 + r) * 32 + 16 + l16] = f2bf(p1[r]);
    }
    short8 pa = *(const short8*)(pw + l16 * 32 + quad * 8);
#pragma unroll
    for (int dt = 0; dt < 4; ++dt) {
      short8 vb = *(const short8*)(vb_base + (size_t)(dt * 16 + l16) * LKK + j0 + quad * 8);
      o[dt] = __builtin_amdgcn_mfma_f32_16x16x32_bf16(pa, vb, o[dt], 0, 0, 0);
    }
  }

#pragma unroll
  for (int dt = 0; dt < 4; ++dt)
#pragma unroll
    for (int r = 0; r < 4; ++r) o_lds[wave][quad * 4 + r][dt * 16 + l16] = o[dt][r];
  if (l16 == 0) {
#pragma unroll
    for (int r = 0; r < 4; ++r) {
      ml_lds[wave][0][quad * 4 + r] = ms[r];
      ml_lds[wave][1][quad * 4 + r] = ls[r];
    }
  }
  __syncthreads();

  const int q = tid >> 4;
  const int d0 = (tid & 15) * 4;
  float mstar = ml_lds[0][0][q];
#pragma unroll
  for (int w = 1; w < 4; ++w) mstar = fmaxf(mstar, ml_lds[w][0][q]);
  float lstar = 0.f, ov[4] = {0.f, 0.f, 0.f, 0.f};
#pragma unroll
  for (int w = 0; w < 4; ++w) {
    const float sc = __builtin_amdgcn_exp2f((ml_lds[w][0][q] - mstar) * LOG2E);
    lstar += ml_lds[w][1][q] * sc;
#pragma unroll
    for (int e = 0; e < 4; ++e) ov[e] += o_lds[w][q][d0 + e] * sc;
  }
  const float inv = 1.0f / lstar;
#pragma unroll
  for (int e = 0; e < 4; ++e)
    attn[(size_t)(b * 16 + q) * 1024 + h * 64 + d0 + e] = ov[e] * inv;
}

__global__ __launch_bounds__(256) void cvt_f32_bf16(const float* __restrict__ src,
                                                    unsigned short* __restrict__ dst,
                                                    int n) {
  const int i = (blockIdx.x * 256 + threadIdx.x) * 4;
  if (i < n) {
    float4 v = *(const float4*)(src + i);
    ushort4v o = {f2bf(v.x), f2bf(v.y), f2bf(v.z), f2bf(v.w)};
    *(ushort4v*)(dst + i) = o;
  }
}

extern "C" void kernel_launch(void* const* d_in, const int* in_sizes, int n_in,
                              void* d_out, int out_size, void* d_ws, size_t ws_size,
                              hipStream_t stream) {
  const float* query = (const float*)d_in[0];
  const float* key = (const float*)d_in[1];
  const float* value = (const float*)d_in[2];
  const float* Wq = (const float*)d_in[3];
  const float* bq = (const float*)d_in[4];
  const float* Wk = (const float*)d_in[5];
  const float* bk = (const float*)d_in[6];
  const float* Wv = (const float*)d_in[7];
  const float* bv = (const float*)d_in[8];
  const float* Wo = (const float*)d_in[9];
  const float* bo = (const float*)d_in[10];
  float* out = (float*)d_out;

  char* ws = (char*)d_ws;
  size_t off = 0;
  auto alloc = [&](size_t bytes) {
    void* p = ws + off;
    off += (bytes + 255) & ~(size_t)255;
    return p;
  };
  unsigned short* Wq_b = (unsigned short*)alloc((size_t)1024 * 1024 * 2);
  unsigned short* Wk_b = (unsigned short*)alloc((size_t)1024 * 1024 * 2);
  unsigned short* Wv_b = (unsigned short*)alloc((size_t)1024 * 1024 * 2);
  unsigned short* Wo_b = (unsigned short*)alloc((size_t)1024 * 1024 * 2);
  unsigned short* q_hd = (unsigned short*)alloc((size_t)8 * 16 * 16 * 64 * 2);
  unsigned short* k_hd = (unsigned short*)alloc((size_t)8 * 16 * 8192 * 64 * 2);
  unsigned short* v_t = (unsigned short*)alloc((size_t)8 * 16 * 64 * 8192 * 2);
  float* attn = (float*)alloc((size_t)128 * 1024 * 4);

  const int wn = 1024 * 1024;
  cvt_f32_bf16<<<1024, 256, 0, stream>>>(Wq, Wq_b, wn);
  cvt_f32_bf16<<<1024, 256, 0, stream>>>(Wk, Wk_b, wn);
  cvt_f32_bf16<<<1024, 256, 0, stream>>>(Wv, Wv_b, wn);
  cvt_f32_bf16<<<1024, 256, 0, stream>>>(Wo, Wo_b, wn);

  // Q: M=128, scale=1/sqrt(64) folded, layout [b][h][16][64]
  gemm_nt<1, 4><<<dim3(1, 8), 256, 0, stream>>>(query, Wq_b, bq, 0.125f, q_hd);
  // K: M=65536, layout [b][h][8192][64]
  gemm_nt<1, 13><<<dim3(512, 8), 256, 0, stream>>>(key, Wk_b, bk, 1.0f, k_hd);
  // V: M=65536, transposed layout [b][h][64][8192]
  gemm_nt<2, 13><<<dim3(512, 8), 256, 0, stream>>>(value, Wv_b, bv, 1.0f, v_t);

  attn_kernel<<<dim3(16, 8), 256, 0, stream>>>(q_hd, k_hd, v_t, attn);

  // Output projection -> d_out fp32 [8,16,1024]
  gemm_nt<0, 0><<<dim3(1, 8), 256, 0, stream>>>(attn, Wo_b, bo, 1.0f, out);
}

// Round 2
// 1055.400 us; speedup vs baseline: 1.2390x; 1.2390x over previous
//
#include <hip/hip_runtime.h>
#include <stdint.h>

#define NHEADS 16
#define LKK 8192
#define SPLIT 8

typedef __attribute__((ext_vector_type(8))) short short8;
typedef __attribute__((ext_vector_type(4))) float f32x4;
typedef __attribute__((ext_vector_type(4))) unsigned short ushort4v;

__device__ __forceinline__ unsigned short f2bf(float f) {
  union { float f; unsigned u; } v; v.f = f;
  unsigned u = v.u;
  return (unsigned short)((u + 0x7fffu + ((u >> 16) & 1u)) >> 16);
}

__device__ __forceinline__ void async_ld16(const void* g, void* l) {
  __builtin_amdgcn_global_load_lds(
      (const __attribute__((address_space(1))) unsigned int*)g,
      (__attribute__((address_space(3))) unsigned int*)l, 16, 0, 0);
}

// Convert up to two fp32 tensors to bf16. gridDim.y selects tensor; each
// block handles 1024 elements (256 threads x float4).
__global__ __launch_bounds__(256) void cvt2(const float* __restrict__ a,
                                            const float* __restrict__ b,
                                            unsigned short* __restrict__ oa,
                                            unsigned short* __restrict__ ob) {
  const float* s = blockIdx.y ? b : a;
  unsigned short* d = blockIdx.y ? ob : oa;
  const size_t i = ((size_t)blockIdx.x * 256 + threadIdx.x) * 4;
  float4 v = *(const float4*)(s + i);
  ushort4v o = {f2bf(v.x), f2bf(v.y), f2bf(v.z), f2bf(v.w)};
  *(ushort4v*)(d + i) = o;
}

// C = A(bf16,[M x 1024]) @ Bw(bf16,[1024 x 1024])^T + bias, NT GEMM.
// 128x128 tile, 4 waves, both operands staged via global_load_lds width-16.
// MODE 0: fp32 row-major out. MODE 1: bf16 out [b][h][x][d] (x = 1<<LOG2ROWS).
// MODE 2: bf16 out transposed [b][h][d][x].
template <int MODE, int LOG2ROWS>
__global__ __launch_bounds__(256) void gemm_nt(
    const unsigned short* __restrict__ A, const unsigned short* __restrict__ Bw,
    const float* __restrict__ bias, float scale, void* __restrict__ outp) {
  __shared__ unsigned short As[128 * 32];
  __shared__ unsigned short Bs[128 * 32];

  const int tid = threadIdx.x;
  const int wave = tid >> 6, lane = tid & 63;
  const int quad = lane >> 4, l16 = lane & 15;
  const int wr = wave >> 1, wc = wave & 1;
  const int bm = blockIdx.x, bn = blockIdx.y;

  f32x4 acc[4][4] = {};

  // Staging: wave w covers tile rows [w*32, w*32+32). Lane i -> row (i>>2),
  // 8-elem segment (i&3). LDS side is wave-uniform base + lane*16B, which
  // lands lane i at shorts [i*8, i*8+8) of a row-major [32][32] wave chunk.
  const int srow = lane >> 2;
  const int sseg = lane & 3;
  const unsigned short* Ag =
      A + (size_t)(bm * 128 + wave * 32 + srow) * 1024 + sseg * 8;
  const unsigned short* Bg =
      Bw + (size_t)(bn * 128 + wave * 32 + srow) * 1024 + sseg * 8;
  unsigned short* AsW = As + wave * 32 * 32;
  unsigned short* BsW = Bs + wave * 32 * 32;

  for (int kk = 0; kk < 32; ++kk) {
    const int k0 = kk * 32;
    __syncthreads();  // protect LDS from previous iter's readers
    async_ld16(Ag + k0, AsW);
    async_ld16(Ag + 16 * 1024 + k0, AsW + 16 * 32);
    async_ld16(Bg + k0, BsW);
    async_ld16(Bg + 16 * 1024 + k0, BsW + 16 * 32);
    __syncthreads();  // drains vmcnt for the async staging

    short8 af[4], bf[4];
#pragma unroll
    for (int i = 0; i < 4; ++i)
      af[i] = *(const short8*)(As + (wr * 64 + i * 16 + l16) * 32 + quad * 8);
#pragma unroll
    for (int j = 0; j < 4; ++j)
      bf[j] = *(const short8*)(Bs + (wc * 64 + j * 16 + l16) * 32 + quad * 8);
#pragma unroll
    for (int i = 0; i < 4; ++i)
#pragma unroll
      for (int j = 0; j < 4; ++j)
        acc[i][j] =
            __builtin_amdgcn_mfma_f32_16x16x32_bf16(af[i], bf[j], acc[i][j], 0, 0, 0);
  }

  float bvals[4];
#pragma unroll
  for (int j = 0; j < 4; ++j) bvals[j] = bias[bn * 128 + wc * 64 + j * 16 + l16];

#pragma unroll
  for (int i = 0; i < 4; ++i) {
    const int gm0 = bm * 128 + wr * 64 + i * 16 + quad * 4;
#pragma unroll
    for (int j = 0; j < 4; ++j) {
      const int gn = bn * 128 + wc * 64 + j * 16 + l16;
      float vals[4];
#pragma unroll
      for (int r = 0; r < 4; ++r) vals[r] = (acc[i][j][r] + bvals[j]) * scale;
      if constexpr (MODE == 0) {
        float* O = (float*)outp;
#pragma unroll
        for (int r = 0; r < 4; ++r) O[(size_t)(gm0 + r) * 1024 + gn] = vals[r];
      } else if constexpr (MODE == 1) {
        unsigned short* O = (unsigned short*)outp;
        const int h = gn >> 6, d = gn & 63;
#pragma unroll
        for (int r = 0; r < 4; ++r) {
          const int m = gm0 + r;
          const int bb = m >> LOG2ROWS;
          const int x = m & ((1 << LOG2ROWS) - 1);
          O[((((size_t)(bb * 16 + h)) << LOG2ROWS) + x) * 64 + d] = f2bf(vals[r]);
        }
      } else {
        unsigned short* O = (unsigned short*)outp;
        const int h = gn >> 6, d = gn & 63;
        const int bb = gm0 >> LOG2ROWS;
        const int x = gm0 & ((1 << LOG2ROWS) - 1);
        ushort4v pk = {f2bf(vals[0]), f2bf(vals[1]), f2bf(vals[2]), f2bf(vals[3])};
        *(ushort4v*)(O + ((((size_t)(bb * 16 + h)) * 64 + d) << LOG2ROWS) + x) = pk;
      }
    }
  }
}

// Split-K flash attention: grid (h=16, b=8, s=SPLIT), 256 threads.
// Block (h,b,s) covers keys [s*1024, +1024); wave w owns 256 of them.
// Writes unnormalized partials (m, l, O) per split.
__global__ __launch_bounds__(256) void attn_split(
    const unsigned short* __restrict__ q_hd,  // [B][H][16][64] bf16 (scale folded)
    const unsigned short* __restrict__ k_hd,  // [B][H][8192][64] bf16
    const unsigned short* __restrict__ v_t,   // [B][H][64][8192] bf16
    float* __restrict__ part_O,               // [B*H][SPLIT][16][64]
    float* __restrict__ part_ml)              // [B*H][SPLIT][2][16]
{
  __shared__ unsigned short p_lds[4][16 * 32];
  __shared__ float o_lds[4][16][64];
  __shared__ float ml_lds[4][2][16];

  const int h = blockIdx.x, b = blockIdx.y, sp = blockIdx.z;
  const int tid = threadIdx.x, wave = tid >> 6, lane = tid & 63;
  const int quad = lane >> 4, l16 = lane & 15;
  const size_t bh = (size_t)(b * NHEADS + h);
  const float LOG2E = 1.44269504088896f;

  const unsigned short* qb = q_hd + bh * (16 * 64) + l16 * 64 + quad * 8;
  short8 aq0 = *(const short8*)(qb);
  short8 aq1 = *(const short8*)(qb + 32);

  const unsigned short* kb_base = k_hd + bh * ((size_t)LKK * 64);
  const unsigned short* vb_base = v_t + bh * ((size_t)64 * LKK);

  float ms[4], ls[4];
  f32x4 o[4] = {};
#pragma unroll
  for (int r = 0; r < 4; ++r) { ms[r] = -3.0e38f; ls[r] = 0.f; }

  unsigned short* pw = &p_lds[wave][0];
  const int jbase = sp * (LKK / SPLIT) + wave * (LKK / SPLIT / 4);

  for (int c = 0; c < (LKK / SPLIT / 4) / 32; ++c) {
    const int j0 = jbase + c * 32;
    short8 kf[2][2];
#pragma unroll
    for (int jt = 0; jt < 2; ++jt)
#pragma unroll
      for (int dh = 0; dh < 2; ++dh)
        kf[jt][dh] = *(const short8*)(kb_base + (size_t)(j0 + jt * 16 + l16) * 64 +
                                      dh * 32 + quad * 8);
    f32x4 s[2];
#pragma unroll
    for (int jt = 0; jt < 2; ++jt) {
      f32x4 z = {};
      z = __builtin_amdgcn_mfma_f32_16x16x32_bf16(aq0, kf[jt][0], z, 0, 0, 0);
      z = __builtin_amdgcn_mfma_f32_16x16x32_bf16(aq1, kf[jt][1], z, 0, 0, 0);
      s[jt] = z;
    }
    float p0[4], p1[4], alpha[4];
#pragma unroll
    for (int r = 0; r < 4; ++r) {
      float v = fmaxf(s[0][r], s[1][r]);
      v = fmaxf(v, __shfl_xor(v, 1));
      v = fmaxf(v, __shfl_xor(v, 2));
      v = fmaxf(v, __shfl_xor(v, 4));
      v = fmaxf(v, __shfl_xor(v, 8));
      const float mn = fmaxf(ms[r], v);
      alpha[r] = __builtin_amdgcn_exp2f((ms[r] - mn) * LOG2E);
      p0[r] = __builtin_amdgcn_exp2f((s[0][r] - mn) * LOG2E);
      p1[r] = __builtin_amdgcn_exp2f((s[1][r] - mn) * LOG2E);
      float rs = p0[r] + p1[r];
      rs += __shfl_xor(rs, 1);
      rs += __shfl_xor(rs, 2);
      rs += __shfl_xor(rs, 4);
      rs += __shfl_xor(rs, 8);
      ls[r] = ls[r] * alpha[r] + rs;
      ms[r] = mn;
    }
#pragma unroll
    for (int dt = 0; dt < 4; ++dt) {
      f32x4 t = o[dt];
      t[0] *= alpha[0]; t[1] *= alpha[1]; t[2] *= alpha[2]; t[3] *= alpha[3];
      o[dt] = t;
    }
    // P: C-layout -> LDS (bf16) -> A-layout
#pragma unroll
    for (int r = 0; r < 4; ++r) {
      pw[(quad * 4 + r) * 32 + l16] = f2bf(p0[r]);
      pw[(quad * 4 + r) * 32 + 16 + l16] = f2bf(p1[r]);
    }
    short8 pa = *(const short8*)(pw + l16 * 32 + quad * 8);
#pragma unroll
    for (int dt = 0; dt < 4; ++dt) {
      short8 vb = *(const short8*)(vb_base + (size_t)(dt * 16 + l16) * LKK + j0 + quad * 8);
      o[dt] = __builtin_amdgcn_mfma_f32_16x16x32_bf16(pa, vb, o[dt], 0, 0, 0);
    }
  }

#pragma unroll
  for (int dt = 0; dt < 4; ++dt)
#pragma unroll
    for (int r = 0; r < 4; ++r) o_lds[wave][quad * 4 + r][dt * 16 + l16] = o[dt][r];
  if (l16 == 0) {
#pragma unroll
    for (int r = 0; r < 4; ++r) {
      ml_lds[wave][0][quad * 4 + r] = ms[r];
      ml_lds[wave][1][quad * 4 + r] = ls[r];
    }
  }
  __syncthreads();

  const int q = tid >> 4;
  const int d0 = (tid & 15) * 4;
  float mstar = ml_lds[0][0][q];
#pragma unroll
  for (int w = 1; w < 4; ++w) mstar = fmaxf(mstar, ml_lds[w][0][q]);
  float lstar = 0.f, ov[4] = {0.f, 0.f, 0.f, 0.f};
#pragma unroll
  for (int w = 0; w < 4; ++w) {
    const float sc = __builtin_amdgcn_exp2f((ml_lds[w][0][q] - mstar) * LOG2E);
    lstar += ml_lds[w][1][q] * sc;
#pragma unroll
    for (int e = 0; e < 4; ++e) ov[e] += o_lds[w][q][d0 + e] * sc;
  }
  const size_t base = (bh * SPLIT + sp);
#pragma unroll
  for (int e = 0; e < 4; ++e) part_O[base * 1024 + q * 64 + d0 + e] = ov[e];
  if (d0 == 0) {
    part_ml[base * 32 + q] = mstar;
    part_ml[base * 32 + 16 + q] = lstar;
  }
}

// Merge SPLIT partials -> bf16 attn activations [B*16][1024] (row b*16+q, col h*64+d).
__global__ __launch_bounds__(256) void attn_merge(const float* __restrict__ part_O,
                                                  const float* __restrict__ part_ml,
                                                  unsigned short* __restrict__ attn_b) {
  const int bh = blockIdx.x;
  const int b = bh >> 4, h = bh & 15;
  const int q = threadIdx.x >> 4;
  const int d0 = (threadIdx.x & 15) * 4;
  const float LOG2E = 1.44269504088896f;

  float mstar = -3.0e38f;
#pragma unroll
  for (int s = 0; s < SPLIT; ++s)
    mstar = fmaxf(mstar, part_ml[((size_t)bh * SPLIT + s) * 32 + q]);
  float lsum = 0.f, ov[4] = {0.f, 0.f, 0.f, 0.f};
#pragma unroll
  for (int s = 0; s < SPLIT; ++s) {
    const size_t base = (size_t)bh * SPLIT + s;
    const float sc = __builtin_amdgcn_exp2f((part_ml[base * 32 + q] - mstar) * LOG2E);
    lsum += part_ml[base * 32 + 16 + q] * sc;
#pragma unroll
    for (int e = 0; e < 4; ++e) ov[e] += part_O[base * 1024 + q * 64 + d0 + e] * sc;
  }
  const float inv = 1.0f / lsum;
  ushort4v pk = {f2bf(ov[0] * inv), f2bf(ov[1] * inv), f2bf(ov[2] * inv),
                 f2bf(ov[3] * inv)};
  *(ushort4v*)(attn_b + (size_t)(b * 16 + q) * 1024 + h * 64 + d0) = pk;
}

extern "C" void kernel_launch(void* const* d_in, const int* in_sizes, int n_in,
                              void* d_out, int out_size, void* d_ws, size_t ws_size,
                              hipStream_t stream) {
  const float* query = (const float*)d_in[0];
  const float* key = (const float*)d_in[1];
  const float* value = (const float*)d_in[2];
  const float* Wq = (const float*)d_in[3];
  const float* bq = (const float*)d_in[4];
  const float* Wk = (const float*)d_in[5];
  const float* bk = (const float*)d_in[6];
  const float* Wv = (const float*)d_in[7];
  const float* bv = (const float*)d_in[8];
  const float* Wo = (const float*)d_in[9];
  const float* bo = (const float*)d_in[10];
  float* out = (float*)d_out;

  char* ws = (char*)d_ws;
  size_t off = 0;
  auto alloc = [&](size_t bytes) {
    void* p = ws + off;
    off += (bytes + 255) & ~(size_t)255;
    return p;
  };
  unsigned short* Wq_b = (unsigned short*)alloc((size_t)1024 * 1024 * 2);
  unsigned short* Wk_b = (unsigned short*)alloc((size_t)1024 * 1024 * 2);
  unsigned short* Wv_b = (unsigned short*)alloc((size_t)1024 * 1024 * 2);
  unsigned short* Wo_b = (unsigned short*)alloc((size_t)1024 * 1024 * 2);
  unsigned short* query_b = (unsigned short*)alloc((size_t)128 * 1024 * 2);
  unsigned short* q_hd = (unsigned short*)alloc((size_t)128 * 1024 * 2);
  unsigned short* attn_b = (unsigned short*)alloc((size_t)128 * 1024 * 2);
  float* part_O = (float*)alloc((size_t)128 * SPLIT * 16 * 64 * 4);
  float* part_ml = (float*)alloc((size_t)128 * SPLIT * 32 * 4);
  unsigned short* k_hd = (unsigned short*)alloc((size_t)128 * LKK * 64 * 2);
  unsigned short* v_t = (unsigned short*)alloc((size_t)128 * LKK * 64 * 2);
  unsigned short* stage = (unsigned short*)alloc((size_t)65536 * 1024 * 2);

  // Weights -> bf16 (4 MB each fp32; 1M elems -> 1024 blocks each)
  cvt2<<<dim3(1024, 2), 256, 0, stream>>>(Wq, Wk, Wq_b, Wk_b);
  cvt2<<<dim3(1024, 2), 256, 0, stream>>>(Wv, Wo, Wv_b, Wo_b);
  // query -> bf16 (131072 elems -> 128 blocks)
  cvt2<<<dim3(128, 1), 256, 0, stream>>>(query, nullptr, query_b, nullptr);

  // Q proj: M=128, scale=1/sqrt(64) folded, layout [b][h][16][64]
  gemm_nt<1, 4><<<dim3(1, 8), 256, 0, stream>>>(query_b, Wq_b, bq, 0.125f, q_hd);

  // key -> bf16 -> K proj (layout [b][h][8192][64])
  cvt2<<<dim3(65536, 1), 256, 0, stream>>>(key, nullptr, stage, nullptr);
  gemm_nt<1, 13><<<dim3(512, 8), 256, 0, stream>>>(stage, Wk_b, bk, 1.0f, k_hd);

  // value -> bf16 (reuse stage) -> V proj (transposed layout [b][h][64][8192])
  cvt2<<<dim3(65536, 1), 256, 0, stream>>>(value, nullptr, stage, nullptr);
  gemm_nt<2, 13><<<dim3(512, 8), 256, 0, stream>>>(stage, Wv_b, bv, 1.0f, v_t);

  // Attention (split-K) + merge -> bf16 activations
  attn_split<<<dim3(16, 8, SPLIT), 256, 0, stream>>>(q_hd, k_hd, v_t, part_O, part_ml);
  attn_merge<<<128, 256, 0, stream>>>(part_O, part_ml, attn_b);

  // Output projection -> d_out fp32 [8,16,1024]
  gemm_nt<0, 0><<<dim3(1, 8), 256, 0, stream>>>(attn_b, Wo_b, bo, 1.0f, out);
}